// Round 15
// baseline (29.789 us; speedup 1.0000x reference)
//
#include <hip/hip_runtime.h>

#define Bn 1024
#define Pn 128
#define Fn 512
#define Dn 256
#define THETA 1e-7f
#define F16_MINN 6.103515625e-5f   // smallest normal f16

typedef _Float16 f16;
typedef f16 f16x8 __attribute__((ext_vector_type(8)));
typedef f16 f16x4 __attribute__((ext_vector_type(4)));
typedef f16 f16x2 __attribute__((ext_vector_type(2)));
typedef float f32x4 __attribute__((ext_vector_type(4)));

// ---------------------------------------------------------------------------
// K1: exact f32 GEMM [x; prototypes] @ fb^T (round-1 body, proven).
// Epilogue emits f16 relu values with positives CLAMPED to f16 min-normal
// (stored > 0 <=> exact f32 v > 0; masks reconstructible in K2).
//   rows <  Bn: RX[b][F]          row-major f16
//   rows >= Bn: RPT8 [F/8][P][8]  8-f groups per p contiguous
// ---------------------------------------------------------------------------
__global__ __launch_bounds__(256)
void gemm_feat(const float* __restrict__ x, const float* __restrict__ prot,
               const float* __restrict__ fb,
               f16* __restrict__ RX, f16* __restrict__ RPT8)
{
    __shared__ float As[64][68];
    __shared__ float Fs[64][68];
    const int tid = threadIdx.x;
    const int rb  = blockIdx.y * 64;
    const int cb  = blockIdx.x * 64;
    const int tx  = tid & 15;
    const int ty  = tid >> 4;
    const int lr  = tid >> 2;
    const int lk  = tid & 3;

    float acc[4][4] = {};

    for (int k0 = 0; k0 < Dn; k0 += 64) {
        #pragma unroll
        for (int q = 0; q < 4; ++q) {
            const int kk = lk + q * 4;
            const int r  = rb + lr;
            const float* asrc = (r < Bn) ? (x + (size_t)r * Dn)
                                         : (prot + (size_t)(r - Bn) * Dn);
            float4 av = *(const float4*)(asrc + k0 + kk * 4);
            float4 fv = *(const float4*)(fb + (size_t)(cb + lr) * Dn + k0 + kk * 4);
            As[kk*4+0][lr] = av.x; As[kk*4+1][lr] = av.y;
            As[kk*4+2][lr] = av.z; As[kk*4+3][lr] = av.w;
            Fs[kk*4+0][lr] = fv.x; Fs[kk*4+1][lr] = fv.y;
            Fs[kk*4+2][lr] = fv.z; Fs[kk*4+3][lr] = fv.w;
        }
        __syncthreads();
        #pragma unroll 8
        for (int k = 0; k < 64; ++k) {
            float4 a = *(const float4*)&As[k][ty * 4];
            float4 f = *(const float4*)&Fs[k][tx * 4];
            const float aa[4] = {a.x, a.y, a.z, a.w};
            const float ff[4] = {f.x, f.y, f.z, f.w};
            #pragma unroll
            for (int i = 0; i < 4; ++i)
                #pragma unroll
                for (int j = 0; j < 4; ++j)
                    acc[i][j] = fmaf(aa[i], ff[j], acc[i][j]);
        }
        __syncthreads();
    }

    const f16 MINN = (f16)F16_MINN;
    #pragma unroll
    for (int i = 0; i < 4; ++i) {
        const int r = rb + ty * 4 + i;
        if (r < Bn) {
            f16x4 rv;
            #pragma unroll
            for (int j = 0; j < 4; ++j) {
                const float v = acc[i][j];
                f16 t = (f16)0;
                if (v > 0.f) { t = (f16)v; if (t < MINN) t = MINN; }
                rv[j] = t;
            }
            *(f16x4*)(RX + (size_t)r * Fn + cb + tx * 4) = rv;
        } else {
            const int p = r - Bn;
            #pragma unroll
            for (int j = 0; j < 4; ++j) {
                const int c = cb + tx * 4 + j;
                const float v = acc[i][j];
                f16 t = (f16)0;
                if (v > 0.f) { t = (f16)v; if (t < MINN) t = MINN; }
                RPT8[(size_t)(c >> 3) * (Pn * 8) + p * 8 + (c & 7)] = t;
            }
        }
    }
}

// ---------------------------------------------------------------------------
// K2 v6: packed-f16 inner math -- NO fdot2 builtin, NO union extraction.
//  Accumulators are f16x2 (v_pk_fma_f16 / v_pk_min / v_pk_add), flushed to
//  f32 every 16 f (2 groups) to bound f16 accumulation error.
//  Chunk extraction via clang .lo/.hi swizzles (register aliases).
//  Masks reconstructed in-register: b = min(r * 65504, 1) (exact 0/1 since
//  K1 clamps positives to >= f16 min-normal; validated round 14).
//  Thread tile 2b x 4p x 64f (slice). Block = 16b x 16p x 8 slices = 256 thr.
//  Grid (Bn/16, Pn/16) = 512 blocks; LDS 32 KB -> 4 blocks/CU.
//  Deterministic LDS slice-reduce; 256 threads write ratios.
// ---------------------------------------------------------------------------
__global__ __launch_bounds__(256)
void tversky_main(const f16* __restrict__ RX, const f16* __restrict__ RPT8,
                  const float* __restrict__ alpha_p, const float* __restrict__ beta_p,
                  float* __restrict__ out)
{
    __shared__ f32x4 sAcc[8][256];           // [slice][local b*16+p] = {I,M,X,P}
    const int tid   = threadIdx.x;
    const int ot    = tid & 31;              // tile-thread 0..31
    const int slice = tid >> 5;              // F-slice 0..7 (64 f each)
    const int bt    = ot >> 2;               // 0..7
    const int pt    = ot & 3;                // 0..3
    const int bb    = blockIdx.x * 16;
    const int pb    = blockIdx.y * 16;
    const int b0    = bb + bt * 2;
    const int p0    = pb + pt * 4;
    const int g0    = slice * 8;             // first f16x8 group of this slice

    float fI[2][4] = {}, fM[2][4] = {}, fX[2][4] = {}, fP[2][4] = {};

    f16x8 KS, ONE8;
    #pragma unroll
    for (int e = 0; e < 8; ++e) { KS[e] = (f16)65504.0f; ONE8[e] = (f16)1; }

    #pragma unroll
    for (int ep = 0; ep < 4; ++ep) {         // 4 epochs x 2 groups = 64 f
        f16x2 aI[2][4] = {}, aM[2][4] = {}, aX[2][4] = {}, aP[2][4] = {};
        #pragma unroll
        for (int gg = 0; gg < 2; ++gg) {
            const int g = g0 + ep * 2 + gg;
            f16x2 rx2[2][4], bx2[2][4], rp2[4][4], bp2[4][4];
            #pragma unroll
            for (int i = 0; i < 2; ++i) {
                const f16x8 v = *(const f16x8*)(RX + (size_t)(b0 + i) * Fn + (size_t)g * 8);
                const f16x8 m = __builtin_elementwise_min(v * KS, ONE8);
                const f16x4 vl = v.lo, vh = v.hi, ml = m.lo, mh = m.hi;
                rx2[i][0] = vl.lo; rx2[i][1] = vl.hi; rx2[i][2] = vh.lo; rx2[i][3] = vh.hi;
                bx2[i][0] = ml.lo; bx2[i][1] = ml.hi; bx2[i][2] = mh.lo; bx2[i][3] = mh.hi;
            }
            const size_t pbase = (size_t)g * (Pn * 8) + (size_t)p0 * 8;
            #pragma unroll
            for (int q = 0; q < 4; ++q) {
                const f16x8 v = *(const f16x8*)(RPT8 + pbase + q * 8);
                const f16x8 m = __builtin_elementwise_min(v * KS, ONE8);
                const f16x4 vl = v.lo, vh = v.hi, ml = m.lo, mh = m.hi;
                rp2[q][0] = vl.lo; rp2[q][1] = vl.hi; rp2[q][2] = vh.lo; rp2[q][3] = vh.hi;
                bp2[q][0] = ml.lo; bp2[q][1] = ml.hi; bp2[q][2] = mh.lo; bp2[q][3] = mh.hi;
            }
            #pragma unroll
            for (int i = 0; i < 2; ++i)
                #pragma unroll
                for (int q = 0; q < 4; ++q)
                    #pragma unroll
                    for (int h = 0; h < 4; ++h) {
                        aI[i][q] = __builtin_elementwise_fma(rx2[i][h], rp2[q][h], aI[i][q]);
                        aM[i][q] = aM[i][q] + __builtin_elementwise_min(rx2[i][h], rp2[q][h]);
                        aX[i][q] = __builtin_elementwise_fma(rx2[i][h], bp2[q][h], aX[i][q]);
                        aP[i][q] = __builtin_elementwise_fma(bx2[i][h], rp2[q][h], aP[i][q]);
                    }
        }
        #pragma unroll
        for (int i = 0; i < 2; ++i)
            #pragma unroll
            for (int q = 0; q < 4; ++q) {
                fI[i][q] += (float)aI[i][q][0] + (float)aI[i][q][1];
                fM[i][q] += (float)aM[i][q][0] + (float)aM[i][q][1];
                fX[i][q] += (float)aX[i][q][0] + (float)aX[i][q][1];
                fP[i][q] += (float)aP[i][q][0] + (float)aP[i][q][1];
            }
    }

    #pragma unroll
    for (int i = 0; i < 2; ++i)
        #pragma unroll
        for (int q = 0; q < 4; ++q) {
            const int outIdx = (bt * 2 + i) * 16 + pt * 4 + q;
            f32x4 v = {fI[i][q], fM[i][q], fX[i][q], fP[i][q]};
            sAcc[slice][outIdx] = v;
        }
    __syncthreads();

    {
        f32x4 acc = sAcc[0][tid];
        #pragma unroll
        for (int s = 1; s < 8; ++s) acc += sAcc[s][tid];
        const float alpha = *alpha_p;
        const float beta  = *beta_p;
        const float I = acc[0], M = acc[1], X = acc[2], P = acc[3];
        const float W = alpha * (X - M) + beta * (P - M);
        const int brow = tid >> 4, pcol = tid & 15;
        out[(size_t)(bb + brow) * Pn + pb + pcol] = I / (I + W + THETA);
    }
}

extern "C" void kernel_launch(void* const* d_in, const int* in_sizes, int n_in,
                              void* d_out, int out_size, void* d_ws, size_t ws_size,
                              hipStream_t stream)
{
    const float* x     = (const float*)d_in[0];
    const float* prot  = (const float*)d_in[1];
    const float* fb    = (const float*)d_in[2];
    const float* alpha = (const float*)d_in[3];
    const float* beta  = (const float*)d_in[4];
    float* out = (float*)d_out;

    f16* RX   = (f16*)d_ws;                   // Bn*Fn f16
    f16* RPT8 = RX + (size_t)Bn * Fn;         // Fn*Pn f16  ([F/8][P][8])

    dim3 gg(Fn / 64, (Bn + Pn) / 64);         // 8 x 18 = 144 blocks
    gemm_feat<<<gg, 256, 0, stream>>>(x, prot, fb, RX, RPT8);

    dim3 gm(Bn / 16, Pn / 16);                // 64 x 8 = 512 blocks
    tversky_main<<<gm, 256, 0, stream>>>(RX, RPT8, alpha, beta, out);
}